// Round 5
// baseline (53.142 us; speedup 1.0000x reference)
//
#include <hip/hip_runtime.h>
#include <math.h>

#define NF   64   // IN_FEATS
#define GRID 512  // 2 blocks/CU on 256 CUs — co-resident under cooperative launch
#define BLK  256

// Device-coherent (agent-scope, LLC-serviced, sc1) access to the S tables.
// Bypasses the non-coherent per-XCD L2s -> no cache fences needed for the
// producer->consumer handoff across the in-kernel barrier.
__device__ __forceinline__ void st_agent(float* p, float v) {
    __hip_atomic_store(p, v, __ATOMIC_RELAXED, __HIP_MEMORY_SCOPE_AGENT);
}
__device__ __forceinline__ float ld_agent(const float* p) {
    return __hip_atomic_load(p, __ATOMIC_RELAXED, __HIP_MEMORY_SCOPE_AGENT);
}

// ---------------------------------------------------------------------------
// Single cooperative kernel, lean hand-rolled barrier (no cg::sync, no
// L2 writeback walks).
// Phase 1: one thread per node. Su[n] = h[n]·W_u + b, Sv[n] = h[n]·W_v.
//   16 independent float4 loads/thread; W uniform (scalar loads).
// Barrier: __syncthreads (drains vmcnt -> S stores are at the coherent
//   point), thread0 atomicAdd + spin until all GRID blocks arrived,
//   __syncthreads. Co-residency guaranteed by cooperative launch.
// Phase 2: 8 edges/thread; int4 index loads; 16 independent agent-scope
//   S gathers; float4 stores. Index dtype detected per-wave (int64 node
//   ids < 2^31 => every odd dword of src is 0).
// ---------------------------------------------------------------------------
__global__ void __launch_bounds__(BLK)
fused_kernel(const float4* __restrict__ h4,
             const float4* __restrict__ W4,
             const float* __restrict__ b,
             const void* __restrict__ srcv,
             const void* __restrict__ dstv,
             float* __restrict__ Su,
             float* __restrict__ Sv,
             unsigned int* __restrict__ cnt,
             float4* __restrict__ out4,
             int nNodes, int nT) {
    int lane = threadIdx.x & 63;
    int odd = ((const int*)srcv)[2 * lane + 1];
    bool is64 = (__ballot(odd == 0) == ~0ull);  // wave-uniform

    int t = blockIdx.x * blockDim.x + threadIdx.x;

    // -------- Phase 1: node scores --------
    if (t < nNodes) {
        const float4* row = h4 + (size_t)t * 16;
        float su = b[0], sv = 0.0f;
        #pragma unroll
        for (int j = 0; j < 16; ++j) {
            float4 x  = row[j];
            float4 wu = W4[j];         // uniform -> stays scalar
            float4 wv = W4[16 + j];
            su += x.x * wu.x + x.y * wu.y + x.z * wu.z + x.w * wu.w;
            sv += x.x * wv.x + x.y * wv.y + x.z * wv.z + x.w * wv.w;
        }
        st_agent(&Su[t], su);
        st_agent(&Sv[t], sv);
    }

    // -------- Lean grid barrier --------
    __syncthreads();  // emits s_waitcnt vmcnt(0): S stores at coherent point
    if (threadIdx.x == 0) {
        __hip_atomic_fetch_add(cnt, 1u, __ATOMIC_RELAXED, __HIP_MEMORY_SCOPE_AGENT);
        while (__hip_atomic_load(cnt, __ATOMIC_RELAXED, __HIP_MEMORY_SCOPE_AGENT) < (unsigned)GRID)
            __builtin_amdgcn_s_sleep(8);
    }
    __syncthreads();  // releases the block; orders phase-2 ops after spin

    // -------- Phase 2: edges --------
    if (t < nT) {
        int si[8], di[8];
        if (is64) {
            const int4* sp = (const int4*)srcv + 4 * t;  // 64 B = 8 int64
            const int4* dp = (const int4*)dstv + 4 * t;
            int4 a = sp[0], b_ = sp[1], c = sp[2], d = sp[3];
            si[0] = a.x; si[1] = a.z; si[2] = b_.x; si[3] = b_.z;
            si[4] = c.x; si[5] = c.z; si[6] = d.x;  si[7] = d.z;
            int4 e = dp[0], f = dp[1], g = dp[2], k = dp[3];
            di[0] = e.x; di[1] = e.z; di[2] = f.x; di[3] = f.z;
            di[4] = g.x; di[5] = g.z; di[6] = k.x; di[7] = k.z;
        } else {
            const int4* sp = (const int4*)srcv + 2 * t;  // 32 B = 8 int32
            const int4* dp = (const int4*)dstv + 2 * t;
            int4 a = sp[0], b_ = sp[1];
            si[0] = a.x;  si[1] = a.y;  si[2] = a.z;  si[3] = a.w;
            si[4] = b_.x; si[5] = b_.y; si[6] = b_.z; si[7] = b_.w;
            int4 e = dp[0], f = dp[1];
            di[0] = e.x; di[1] = e.y; di[2] = e.z; di[3] = e.w;
            di[4] = f.x; di[5] = f.y; di[6] = f.z; di[7] = f.w;
        }

        float su[8], dv[8];
        #pragma unroll
        for (int j = 0; j < 8; ++j) su[j] = ld_agent(&Su[si[j]]);  // independent
        #pragma unroll
        for (int j = 0; j < 8; ++j) dv[j] = ld_agent(&Sv[di[j]]);

        float o[8];
        #pragma unroll
        for (int j = 0; j < 8; ++j) {
            float l = su[j] + dv[j];                 // bias already in Su
            o[j] = 1.0f / (1.0f + __expf(-l));
        }
        out4[2 * t]     = make_float4(o[0], o[1], o[2], o[3]);
        out4[2 * t + 1] = make_float4(o[4], o[5], o[6], o[7]);
    }
}

extern "C" void kernel_launch(void* const* d_in, const int* in_sizes, int n_in,
                              void* d_out, int out_size, void* d_ws, size_t ws_size,
                              hipStream_t stream) {
    const float4* h4  = (const float4*)d_in[0];
    const void*   src = d_in[1];
    const void*   dst = d_in[2];
    const float4* W4  = (const float4*)d_in[3];
    const float*  b   = (const float*)d_in[4];
    float4* out4 = (float4*)d_out;

    int nNodes = in_sizes[0] / NF;   // 50000
    int nE     = in_sizes[1];        // 800000
    int nT     = nE / 8;             // 100000

    unsigned int* cnt = (unsigned int*)d_ws;
    float* Su = (float*)((char*)d_ws + 1024);            // 200 KB
    float* Sv = (float*)((char*)d_ws + 1024 + 204800);   // 200 KB

    // Deterministic per-call barrier-counter init (fixes 0xAA poison too).
    hipMemsetAsync(d_ws, 0, 4, stream);

    void* args[] = { (void*)&h4, (void*)&W4, (void*)&b, (void*)&src, (void*)&dst,
                     (void*)&Su, (void*)&Sv, (void*)&cnt, (void*)&out4,
                     (void*)&nNodes, (void*)&nT };
    hipLaunchCooperativeKernel((void*)fused_kernel, dim3(GRID), dim3(BLK),
                               args, 0, stream);
}

// Round 7
// 18.649 us; speedup vs baseline: 2.8496x; 2.8496x over previous
//
#include <hip/hip_runtime.h>
#include <math.h>

#define NF 64  // IN_FEATS

typedef int   vint4   __attribute__((ext_vector_type(4)));
typedef float vfloat4 __attribute__((ext_vector_type(4)));

// ---------------------------------------------------------------------------
// Kernel 1: per-node scores.  S[n] = (h[n]·W_u + b,  h[n]·W_v)
// One thread per node: 16 independent float4 loads (256 B/thread), W uniform
// (scalar loads), dual dot product, single 8 B store. No shuffles.
// ---------------------------------------------------------------------------
__global__ void __launch_bounds__(256)
node_scores_kernel(const float4* __restrict__ h4,
                   const float4* __restrict__ W4,
                   const float* __restrict__ b,
                   float2* __restrict__ S, int nNodes) {
    int n = blockIdx.x * blockDim.x + threadIdx.x;
    if (n >= nNodes) return;

    const float4* row = h4 + (size_t)n * 16;
    float su = b[0], sv = 0.0f;
    #pragma unroll
    for (int j = 0; j < 16; ++j) {
        float4 x  = row[j];
        float4 wu = W4[j];        // uniform -> stays scalar
        float4 wv = W4[16 + j];
        su += x.x * wu.x + x.y * wu.y + x.z * wu.z + x.w * wu.w;
        sv += x.x * wv.x + x.y * wv.y + x.z * wv.z + x.w * wv.w;
    }
    S[n] = make_float2(su, sv);
}

// ---------------------------------------------------------------------------
// Kernel 2: out[e] = sigmoid(S[src[e]].x + S[dst[e]].y), 8 edges/thread.
// Index loads + output stores are nontemporal (touched once; keeps the hot
// 400 KB S table resident in each XCD L2). S gathers are normal cached loads
// (~200 cy L2). Index dtype (int64 vs int32) detected per-wave from the
// first 512 B of src (int64 node ids < 2^31 => every odd dword is 0).
// ---------------------------------------------------------------------------
__global__ void __launch_bounds__(256)
edge_kernel(const void* __restrict__ srcv,
            const void* __restrict__ dstv,
            const float2* __restrict__ S,
            float* __restrict__ out, int nT) {
    int lane = threadIdx.x & 63;
    int odd = ((const int*)srcv)[2 * lane + 1];
    bool is64 = (__ballot(odd == 0) == ~0ull);  // wave-uniform

    int t = blockIdx.x * blockDim.x + threadIdx.x;
    if (t >= nT) return;

    int si[8], di[8];
    if (is64) {
        const vint4* sp = (const vint4*)srcv + 4 * t;  // 64 B = 8 int64
        const vint4* dp = (const vint4*)dstv + 4 * t;
        vint4 a  = __builtin_nontemporal_load(sp);
        vint4 b_ = __builtin_nontemporal_load(sp + 1);
        vint4 c  = __builtin_nontemporal_load(sp + 2);
        vint4 d  = __builtin_nontemporal_load(sp + 3);
        si[0] = a.x; si[1] = a.z; si[2] = b_.x; si[3] = b_.z;
        si[4] = c.x; si[5] = c.z; si[6] = d.x;  si[7] = d.z;
        vint4 e = __builtin_nontemporal_load(dp);
        vint4 f = __builtin_nontemporal_load(dp + 1);
        vint4 g = __builtin_nontemporal_load(dp + 2);
        vint4 k = __builtin_nontemporal_load(dp + 3);
        di[0] = e.x; di[1] = e.z; di[2] = f.x; di[3] = f.z;
        di[4] = g.x; di[5] = g.z; di[6] = k.x; di[7] = k.z;
    } else {
        const vint4* sp = (const vint4*)srcv + 2 * t;  // 32 B = 8 int32
        const vint4* dp = (const vint4*)dstv + 2 * t;
        vint4 a  = __builtin_nontemporal_load(sp);
        vint4 b_ = __builtin_nontemporal_load(sp + 1);
        si[0] = a.x;  si[1] = a.y;  si[2] = a.z;  si[3] = a.w;
        si[4] = b_.x; si[5] = b_.y; si[6] = b_.z; si[7] = b_.w;
        vint4 e = __builtin_nontemporal_load(dp);
        vint4 f = __builtin_nontemporal_load(dp + 1);
        di[0] = e.x; di[1] = e.y; di[2] = e.z; di[3] = e.w;
        di[4] = f.x; di[5] = f.y; di[6] = f.z; di[7] = f.w;
    }

    float2 su[8], dv[8];
    #pragma unroll
    for (int j = 0; j < 8; ++j) su[j] = S[si[j]];   // independent L2 gathers
    #pragma unroll
    for (int j = 0; j < 8; ++j) dv[j] = S[di[j]];

    float o[8];
    #pragma unroll
    for (int j = 0; j < 8; ++j) {
        float l = su[j].x + dv[j].y;                // bias already in S.x
        o[j] = 1.0f / (1.0f + __expf(-l));
    }
    vfloat4* o4 = (vfloat4*)(out + 8 * (size_t)t);
    vfloat4 lo = { o[0], o[1], o[2], o[3] };
    vfloat4 hi = { o[4], o[5], o[6], o[7] };
    __builtin_nontemporal_store(lo, o4);
    __builtin_nontemporal_store(hi, o4 + 1);
}

extern "C" void kernel_launch(void* const* d_in, const int* in_sizes, int n_in,
                              void* d_out, int out_size, void* d_ws, size_t ws_size,
                              hipStream_t stream) {
    const float4* h4  = (const float4*)d_in[0];
    const void*   src = d_in[1];
    const void*   dst = d_in[2];
    const float4* W4  = (const float4*)d_in[3];
    const float*  b   = (const float*)d_in[4];
    float* out = (float*)d_out;

    int nNodes = in_sizes[0] / NF;   // 50000
    int nE     = in_sizes[1];        // 800000

    float2* S = (float2*)d_ws;       // 50000*8 B = 400 KB scratch

    int nodeBlocks = (nNodes + 255) / 256;       // 196 blocks of 256
    node_scores_kernel<<<nodeBlocks, 256, 0, stream>>>(h4, W4, b, S, nNodes);

    int nT = nE / 8;                             // 100000 threads
    int edgeBlocks = (nT + 255) / 256;           // 391 blocks of 256
    edge_kernel<<<edgeBlocks, 256, 0, stream>>>(src, dst, S, out, nT);
}